// Round 1
// baseline (373.777 us; speedup 1.0000x reference)
//
#include <hip/hip_runtime.h>
#include <hip/hip_bf16.h>

// ---------- types ----------
typedef unsigned short u16;
typedef __attribute__((ext_vector_type(4))) float f32x4;
typedef __attribute__((ext_vector_type(8))) short short8;   // 8 bf16 for MFMA operands
typedef __attribute__((ext_vector_type(8))) u16 u16x8;

__device__ __forceinline__ f32x4 fzero() { f32x4 z = {0.f, 0.f, 0.f, 0.f}; return z; }

// f32 -> bf16 bits, round-to-nearest-even (normals; inputs here are tame)
__device__ __forceinline__ u16 f2b(float x) {
  unsigned u = __builtin_bit_cast(unsigned, x);
  unsigned r = (u + 0x7fffu + ((u >> 16) & 1u)) >> 16;
  return (u16)r;
}

// ---------- problem constants ----------
#define BS 4096
#define IN_ 256
#define H_ 256
#define G_ 64
#define E_ 256
#define A_ 30
#define NW 65536      // IN*H
#define NH 65792      // NW + H

// ---------- ws offsets (bytes) ----------
#define OFF_W2B   0UL            // 33,685,504  (257*8*256*32 bf16, k-sliced layout)
#define OFF_HIDB  33685504UL     //  2,097,152
#define OFF_GOALB 35782656UL     //    524,288
#define OFF_W1B   36306944UL     //     32,768
#define OFF_FEWB  36339712UL     //    131,072
#define OFF_WIHB  36470784UL     //    393,216
#define OFF_WHHB  36864000UL     //    393,216
#define OFF_H1B   37257216UL     //  2,097,152
#define OFF_XIN   39354368UL     //  4,194,304  (reused later: yb, xfb)
#define OFF_PART  43548672UL     // 33,554,432  (reused later: gi, gh)
// total ~77.1 MB

// ================= K_convert: f32->bf16 for all weights/activations =================
// w2 gets a k-slice-contiguous layout: elem(n,k) -> [((i*8+ks)*256+h)*32+kk],
// i=n>>8, h=n&255, ks=k>>5, kk=k&31. So slice (i,ks) is one contiguous 16KB blob.
#define NC_W2   2105344L
#define NC_HID  131072L
#define NC_GOAL 32768L
#define NC_W1   2048L
#define NC_FE   8192L
#define NC_WIH  24576L
#define NC_WHH  24576L
#define NC_TOT  (NC_W2+NC_HID+NC_GOAL+NC_W1+NC_FE+NC_WIH+NC_WHH)  // 2,328,576

__global__ void k_convert(const float* __restrict__ w2, const float* __restrict__ hid,
                          const float* __restrict__ goal, const float* __restrict__ w1,
                          const float* __restrict__ fw, const float* __restrict__ wih,
                          const float* __restrict__ whh,
                          u16* __restrict__ w2b, u16* __restrict__ hidb, u16* __restrict__ goalb,
                          u16* __restrict__ w1b, u16* __restrict__ fwb, u16* __restrict__ wihb,
                          u16* __restrict__ whhb) {
  long cid = (long)blockIdx.x * 256 + threadIdx.x;  // one 8-elem chunk per thread
  const float* src; u16* dst; long si, di;
  long c = cid;
  if (c < NC_W2) {
    long e = c * 8;
    long n = e >> 8; int k0 = (int)(e & 255);
    int i = (int)(n >> 8), h = (int)(n & 255), ks = k0 >> 5, kk = k0 & 31;
    si = e; di = ((long)(i * 8 + ks) * 256 + h) * 32 + kk;
    src = w2; dst = w2b;
  } else if ((c -= NC_W2) < NC_HID)  { si = di = c * 8; src = hid;  dst = hidb; }
  else if ((c -= NC_HID) < NC_GOAL)  { si = di = c * 8; src = goal; dst = goalb; }
  else if ((c -= NC_GOAL) < NC_W1)   { si = di = c * 8; src = w1;   dst = w1b; }
  else if ((c -= NC_W1) < NC_FE)     { si = di = c * 8; src = fw;   dst = fwb; }
  else if ((c -= NC_FE) < NC_WIH)    { si = di = c * 8; src = wih;  dst = wihb; }
  else if ((c -= NC_WIH) < NC_WHH)   { si = di = c * 8; src = whh;  dst = whhb; }
  else return;
  f32x4 a = *(const f32x4*)(src + si);
  f32x4 b = *(const f32x4*)(src + si + 4);
  u16x8 o;
  o[0]=f2b(a[0]); o[1]=f2b(a[1]); o[2]=f2b(a[2]); o[3]=f2b(a[3]);
  o[4]=f2b(b[0]); o[5]=f2b(b[1]); o[6]=f2b(b[2]); o[7]=f2b(b[3]);
  *(u16x8*)(dst + di) = o;
}

// ================= block-wide mean/inv-std over 256 elems (256 thr) =================
__device__ __forceinline__ void blk_ln(float v, float* red, int t, float& mu, float& inv) {
  float s = v, sq = v * v;
  #pragma unroll
  for (int o = 32; o; o >>= 1) { s += __shfl_xor(s, o); sq += __shfl_xor(sq, o); }
  int w = t >> 6;
  if ((t & 63) == 0) { red[w] = s; red[4 + w] = sq; }
  __syncthreads();
  float S = red[0] + red[1] + red[2] + red[3];
  float Q = red[4] + red[5] + red[6] + red[7];
  mu = S * (1.f / 256.f);
  float var = Q * (1.f / 256.f) - mu * mu;
  inv = rsqrtf(var + 1e-5f);
  __syncthreads();
}

// ================= K_ln1: x_in = LN(inputs)*g+b (f32) =================
__global__ void k_ln1(const float* __restrict__ inp, const float* __restrict__ g,
                      const float* __restrict__ b, float* __restrict__ xin) {
  int bb = blockIdx.x, t = threadIdx.x;
  __shared__ float red[8];
  float v = inp[(long)bb * 256 + t];
  float mu, inv; blk_ln(v, red, t, mu, inv);
  xin[(long)bb * 256 + t] = (v - mu) * inv * g[t] + b[t];
}

// ================= generic bt-GEMM: C[M][N] = epi(A_bf16[M][K] @ B_bf16[N][K]^T + bias) ==========
// EPI: 0 = relu -> bf16 ; 1 = bias -> bf16 ; 2 = bias -> f32
template<int K, int EPI>
__global__ __launch_bounds__(256) void k_gemm(const u16* __restrict__ Ab, const u16* __restrict__ Bb,
                                              const float* __restrict__ bias,
                                              float* __restrict__ Cf, u16* __restrict__ Cb,
                                              int N, int ntiles) {
  constexpr int PIT = K + 8;       // +8 bf16 pad -> even 16B-slot spread on b128 reads
  __shared__ u16 As[128 * PIT];
  __shared__ u16 Bs[128 * PIT];
  const int t = threadIdx.x;
  const int mt = blockIdx.x / ntiles, nt = blockIdx.x % ntiles;
  const int m0 = mt * 128, n0 = nt * 128;
  constexpr int CPR = K / 8;
  #pragma unroll
  for (int j = 0; j < K / 16; ++j) {
    int q = t + 256 * j;
    int row = q / CPR, cc = q % CPR;
    *(u16x8*)&As[row * PIT + cc * 8] = *(const u16x8*)(Ab + (long)(m0 + row) * K + cc * 8);
    *(u16x8*)&Bs[row * PIT + cc * 8] = *(const u16x8*)(Bb + (long)(n0 + row) * K + cc * 8);
  }
  __syncthreads();
  const int lane = t & 63, wid = t >> 6;
  const int la = lane & 15, lb = lane >> 4;
  const int r0 = (wid >> 1) * 64, c0 = (wid & 1) * 64;
  f32x4 acc[4][4];
  #pragma unroll
  for (int m = 0; m < 4; ++m)
    #pragma unroll
    for (int n = 0; n < 4; ++n) acc[m][n] = fzero();
  #pragma unroll
  for (int ks = 0; ks < K / 32; ++ks) {
    short8 af[4], bf[4];
    #pragma unroll
    for (int m = 0; m < 4; ++m) af[m] = *(const short8*)&As[(r0 + m * 16 + la) * PIT + ks * 32 + lb * 8];
    #pragma unroll
    for (int n = 0; n < 4; ++n) bf[n] = *(const short8*)&Bs[(c0 + n * 16 + la) * PIT + ks * 32 + lb * 8];
    #pragma unroll
    for (int m = 0; m < 4; ++m)
      #pragma unroll
      for (int n = 0; n < 4; ++n)
        acc[m][n] = __builtin_amdgcn_mfma_f32_16x16x32_bf16(af[m], bf[n], acc[m][n], 0, 0, 0);
  }
  #pragma unroll
  for (int n = 0; n < 4; ++n) {
    int gc = n0 + c0 + n * 16 + la;
    float bv = bias[gc];
    #pragma unroll
    for (int m = 0; m < 4; ++m) {
      int gr = m0 + r0 + m * 16 + lb * 4;
      #pragma unroll
      for (int r = 0; r < 4; ++r) {
        float v = acc[m][n][r] + bv;
        if (EPI == 0) v = fmaxf(v, 0.f);
        if (EPI <= 1) Cb[(long)(gr + r) * N + gc] = f2b(v);
        else          Cf[(long)(gr + r) * N + gc] = v;
      }
    }
  }
}

// ================= K_big: fused hypernet GEMM + tanh*3 + einsum contraction ==========
// grid 512 = 64 btiles x 8 islices (islice = bx&7 -> XCD-pinned w2 chunk).
// block: 256 thr (4 waves side-by-side in h), tile 64b x 256h, K=256 per i, 32(33) i's.
// LDS: A (h1 tile, resident) 33KB + B slice dbuf 2x20KB = 74.75KB -> 2 blocks/CU.
__global__ __launch_bounds__(256, 2) void k_big(const u16* __restrict__ w2b, const u16* __restrict__ h1b,
                                                const float* __restrict__ xin, const float* __restrict__ b2,
                                                float* __restrict__ part) {
  const int bx = blockIdx.x;
  const int islice = bx & 7, btile = bx >> 3;
  const int b0 = btile * 64;
  const int i0 = islice * 32;
  const int ni = (islice == 7) ? 33 : 32;   // islice 7 also does the bias row-block (i==256)
  const int NST = ni * 8;
  const int t = threadIdx.x, lane = t & 63, wid = t >> 6;
  const int la = lane & 15, lb = lane >> 4;
  const int c0 = wid * 64;

  __shared__ u16 As[64 * 264];        // h1 tile, pitch 264 (pad 8)
  __shared__ u16 Bsh[2][256 * 40];    // w2 slice dbuf, pitch 40 (pad 8)

  // stage A (h1[b0..b0+64) x 256) once
  #pragma unroll
  for (int j = 0; j < 8; ++j) {
    int q = t + 256 * j;
    int row = q >> 5, cc = q & 31;
    *(u16x8*)&As[row * 264 + cc * 8] = *(const u16x8*)(h1b + (long)(b0 + row) * 256 + cc * 8);
  }

  u16x8 stgA[4], stgB[4];
  // prologue: slice 0 -> LDS buf0 ; slice 1 -> stgB
  {
    const u16* p = w2b + (long)(i0 * 8 + 0) * 8192 + t * 8;
    #pragma unroll
    for (int j = 0; j < 4; ++j) stgA[j] = *(const u16x8*)(p + 2048 * j);
    #pragma unroll
    for (int j = 0; j < 4; ++j) { int q = t + 256 * j; *(u16x8*)&Bsh[0][(q >> 2) * 40 + (q & 3) * 8] = stgA[j]; }
    p = w2b + (long)(i0 * 8 + 1) * 8192 + t * 8;
    #pragma unroll
    for (int j = 0; j < 4; ++j) stgB[j] = *(const u16x8*)(p + 2048 * j);
  }
  __syncthreads();

  f32x4 accT[4][4];
  #pragma unroll
  for (int m = 0; m < 4; ++m)
    #pragma unroll
    for (int n = 0; n < 4; ++n) accT[m][n] = fzero();

  f32x4 cf[4][4];

  // one k-step: read frags of buf 'bcur', prefetch slice sn+2 into 'ldd',
  // ds_write slice sn+1 (in 'wsr') into 'bnxt', 16 MFMA, barrier.
  auto step = [&](int ks, int sn, u16x8 (&ldd)[4], u16x8 (&wsr)[4], u16* bcur, u16* bnxt) {
    if (sn + 2 < NST) {
      const u16* p = w2b + ((long)(i0 * 8) + sn + 2) * 8192 + t * 8;
      #pragma unroll
      for (int j = 0; j < 4; ++j) ldd[j] = *(const u16x8*)(p + 2048 * j);
    }
    short8 af[4], bf[4];
    #pragma unroll
    for (int m = 0; m < 4; ++m) af[m] = *(const short8*)&As[(m * 16 + la) * 264 + ks * 32 + lb * 8];
    #pragma unroll
    for (int n = 0; n < 4; ++n) bf[n] = *(const short8*)(bcur + (c0 + n * 16 + la) * 40 + lb * 8);
    if (sn + 1 < NST) {
      #pragma unroll
      for (int j = 0; j < 4; ++j) { int q = t + 256 * j; *(u16x8*)(bnxt + (q >> 2) * 40 + (q & 3) * 8) = wsr[j]; }
    }
    if (ks == 0) {
      #pragma unroll
      for (int m = 0; m < 4; ++m)
        #pragma unroll
        for (int n = 0; n < 4; ++n)
          cf[m][n] = __builtin_amdgcn_mfma_f32_16x16x32_bf16(af[m], bf[n], fzero(), 0, 0, 0);
    } else {
      #pragma unroll
      for (int m = 0; m < 4; ++m)
        #pragma unroll
        for (int n = 0; n < 4; ++n)
          cf[m][n] = __builtin_amdgcn_mfma_f32_16x16x32_bf16(af[m], bf[n], cf[m][n], 0, 0, 0);
    }
    __syncthreads();
  };

  for (int ii = 0; ii < ni; ++ii) {
    const int ig = i0 + ii;
    const bool isb = (ig == 256);
    const int ic = isb ? 0 : ig;
    // per-i scalars: x_in[b][i] (or 1 for bias block) and hy_b2[n] — issued early
    f32x4 xv[4];
    #pragma unroll
    for (int m = 0; m < 4; ++m)
      #pragma unroll
      for (int r = 0; r < 4; ++r)
        xv[m][r] = isb ? 1.f : __ldg(xin + (long)(b0 + m * 16 + lb * 4 + r) * 256 + ic);
    float b2v[4];
    #pragma unroll
    for (int n = 0; n < 4; ++n) b2v[n] = __ldg(b2 + (long)ig * 256 + c0 + n * 16 + la);

    #pragma unroll
    for (int ks = 0; ks < 8; ++ks) {
      const int sn = ii * 8 + ks;
      if ((ks & 1) == 0) step(ks, sn, stgA, stgB, &Bsh[0][0], &Bsh[1][0]);
      else               step(ks, sn, stgB, stgA, &Bsh[1][0], &Bsh[0][0]);
    }
    // epilogue: w = 3*tanh(pre) via odd poly (|pre| <= ~0.58 by Cauchy-Schwarz), accumulate
    #pragma unroll
    for (int m = 0; m < 4; ++m)
      #pragma unroll
      for (int n = 0; n < 4; ++n)
        #pragma unroll
        for (int r = 0; r < 4; ++r) {
          float pre = cf[m][n][r] + b2v[n];
          float t2 = pre * pre;
          float w = pre * fmaf(t2, fmaf(t2, fmaf(t2, -0.161905f, 0.4f), -1.0f), 3.0f);
          accT[m][n][r] = fmaf(xv[m][r], w, accT[m][n][r]);
        }
  }

  float* dst = part + (long)islice * (4096 * 256);
  #pragma unroll
  for (int m = 0; m < 4; ++m)
    #pragma unroll
    for (int n = 0; n < 4; ++n)
      #pragma unroll
      for (int r = 0; r < 4; ++r)
        dst[(long)(b0 + m * 16 + lb * 4 + r) * 256 + (c0 + n * 16 + la)] = accT[m][n][r];
}

// ================= K_redln: x = sum(partials); y = relu(LN2(x)) -> bf16 =================
__global__ void k_redln(const float* __restrict__ part, const float* __restrict__ g,
                        const float* __restrict__ b, u16* __restrict__ yb) {
  int bb = blockIdx.x, t = threadIdx.x;
  __shared__ float red[8];
  float s = 0.f;
  #pragma unroll
  for (int sl = 0; sl < 8; ++sl) s += part[(long)sl * (4096 * 256) + (long)bb * 256 + t];
  float mu, inv; blk_ln(s, red, t, mu, inv);
  float v = (s - mu) * inv * g[t] + b[t];
  yb[(long)bb * 256 + t] = f2b(fmaxf(v, 0.f));
}

// ================= K_gru: GRU cell + dueling heads =================
__global__ void k_gru(const float* __restrict__ gi, const float* __restrict__ gh,
                      const float* __restrict__ hin,
                      const float* __restrict__ vw, const float* __restrict__ vb,
                      const float* __restrict__ aw, const float* __restrict__ ab,
                      float* __restrict__ qout, float* __restrict__ hout) {
  int bb = blockIdx.x, t = threadIdx.x;
  const float* gib = gi + (long)bb * 768;
  const float* ghb = gh + (long)bb * 768;
  float ir = gib[t], iz = gib[256 + t], inx = gib[512 + t];
  float hr = ghb[t], hz = ghb[256 + t], hn = ghb[512 + t];
  float hprev = hin[(long)bb * 256 + t];
  float r = 1.f / (1.f + expf(-(ir + hr)));
  float z = 1.f / (1.f + expf(-(iz + hz)));
  float n = tanhf(inx + r * hn);
  float h = (1.f - z) * n + z * hprev;
  hout[(long)bb * 256 + t] = h;
  __shared__ float hl[256];
  __shared__ float ov[32];
  __shared__ float mred;
  hl[t] = h;
  __syncthreads();
  int gidx = t >> 3, lg = t & 7;
  if (gidx < 31) {
    const float* wr = (gidx < 30) ? (aw + (long)gidx * 256) : vw;
    float p = 0.f;
    #pragma unroll 8
    for (int j = 0; j < 32; ++j) p += hl[lg + 8 * j] * wr[lg + 8 * j];
    p += __shfl_xor(p, 1); p += __shfl_xor(p, 2); p += __shfl_xor(p, 4);
    if (lg == 0) ov[gidx] = p + ((gidx < 30) ? ab[gidx] : vb[0]);
  }
  __syncthreads();
  if (t == 0) {
    float m = 0.f;
    #pragma unroll
    for (int a = 0; a < 30; ++a) m += ov[a];
    mred = m * (1.f / 30.f);
  }
  __syncthreads();
  if (t < 30) qout[(long)bb * 30 + t] = ov[30] + ov[t] - mred;
}

// ================= launch =================
extern "C" void kernel_launch(void* const* d_in, const int* in_sizes, int n_in,
                              void* d_out, int out_size, void* d_ws, size_t ws_size,
                              hipStream_t stream) {
  const float* inputs = (const float*)d_in[0];
  const float* hidden = (const float*)d_in[1];
  const float* goal   = (const float*)d_in[2];
  const float* ln1g   = (const float*)d_in[3];
  const float* ln1b   = (const float*)d_in[4];
  const float* hyw1   = (const float*)d_in[5];
  const float* hyb1   = (const float*)d_in[6];
  const float* hyw2   = (const float*)d_in[7];
  const float* hyb2   = (const float*)d_in[8];
  const float* ln2g   = (const float*)d_in[9];
  const float* ln2b   = (const float*)d_in[10];
  const float* few    = (const float*)d_in[11];
  const float* feb    = (const float*)d_in[12];
  const float* wih    = (const float*)d_in[13];
  const float* whh    = (const float*)d_in[14];
  const float* bih    = (const float*)d_in[15];
  const float* bhh    = (const float*)d_in[16];
  const float* valw   = (const float*)d_in[17];
  const float* valb   = (const float*)d_in[18];
  const float* advw   = (const float*)d_in[19];
  const float* advb   = (const float*)d_in[20];

  char* ws = (char*)d_ws;
  u16* w2b   = (u16*)(ws + OFF_W2B);
  u16* hidb  = (u16*)(ws + OFF_HIDB);
  u16* goalb = (u16*)(ws + OFF_GOALB);
  u16* w1b   = (u16*)(ws + OFF_W1B);
  u16* fwb   = (u16*)(ws + OFF_FEWB);
  u16* wihb  = (u16*)(ws + OFF_WIHB);
  u16* whhb  = (u16*)(ws + OFF_WHHB);
  u16* h1b   = (u16*)(ws + OFF_H1B);
  float* xin = (float*)(ws + OFF_XIN);
  float* prt = (float*)(ws + OFF_PART);
  u16* yb    = (u16*)(ws + OFF_XIN);                 // aliases xin (dead after k_big)
  u16* xfb   = (u16*)(ws + OFF_XIN + 2097152UL);
  float* gim = (float*)(ws + OFF_PART);              // aliases part (dead after k_redln)
  float* ghm = (float*)(ws + OFF_PART + 12582912UL);
  float* qout = (float*)d_out;
  float* hout = qout + (long)BS * A_;

  k_convert<<<9096, 256, 0, stream>>>(hyw2, hidden, goal, hyw1, few, wih, whh,
                                      w2b, hidb, goalb, w1b, fwb, wihb, whhb);
  k_ln1<<<BS, 256, 0, stream>>>(inputs, ln1g, ln1b, xin);
  k_gemm<64, 0><<<64, 256, 0, stream>>>(goalb, w1b, hyb1, nullptr, h1b, 256, 2);   // h1 (relu)
  k_big<<<512, 256, 0, stream>>>(w2b, h1b, xin, hyb2, prt);
  k_redln<<<BS, 256, 0, stream>>>(prt, ln2g, ln2b, yb);
  k_gemm<256, 1><<<64, 256, 0, stream>>>(yb, fwb, feb, nullptr, xfb, 256, 2);      // fe
  k_gemm<256, 2><<<192, 256, 0, stream>>>(xfb, wihb, bih, gim, nullptr, 768, 6);   // gi
  k_gemm<256, 2><<<192, 256, 0, stream>>>(hidb, whhb, bhh, ghm, nullptr, 768, 6);  // gh
  k_gru<<<BS, 256, 0, stream>>>(gim, ghm, hidden, valw, valb, advw, advb, qout, hout);
}